// Round 8
// baseline (291.221 us; speedup 1.0000x reference)
//
#include <hip/hip_runtime.h>
#include <hip/hip_fp16.h>

#define LRELU(v) ((v) > 0.0f ? (v) : 0.2f * (v))

constexpr int F_IN = 128;
constexpr int NH1  = 6;
constexpr int D1   = 192;   // NH1 * 32

typedef _Float16 half8 __attribute__((ext_vector_type(8)));
typedef float floatx4 __attribute__((ext_vector_type(4)));

__device__ __forceinline__ void wave_lds_fence() {
  __builtin_amdgcn_wave_barrier();
  asm volatile("s_waitcnt lgkmcnt(0)" ::: "memory");
  __builtin_amdgcn_wave_barrier();
}

// ---------------- fused: histogram (blocks [0,HB)) | MFMA gemm1 (blocks [HB,..)) ----------------
// hist: pose[e] = rank of edge e within its dst segment (atomic return).
// gemm: h1h[N,192] = fp16(x @ W1), als/ald[N,6] fused epilogue.
// W1 is converted fp32->fp16 transposed per 32-K chunk into LDS (stride 40 halfs:
// 80 B rows -> 16B-aligned b128 reads, banks spread, 2-way max aliasing = free).
__global__ __launch_bounds__(256) void k_fused(
    const int* __restrict__ dst, int* __restrict__ cnt, int* __restrict__ pose,
    const float* __restrict__ x, const float* __restrict__ W1,
    const float* __restrict__ a1s, const float* __restrict__ a1d,
    __half* __restrict__ h1h, float* __restrict__ als, float* __restrict__ ald,
    int N, int E, int HB) {
  if ((int)blockIdx.x < HB) {
    int e = blockIdx.x * 256 + threadIdx.x;
    if (e < E) pose[e] = atomicAdd(&cnt[dst[e]], 1);
    return;
  }

  __shared__ _Float16 wlds[192][40];
  int wv = ((int)blockIdx.x - HB) * 4 + (threadIdx.x >> 6);
  int m0 = wv * 16;
  int lane = threadIdx.x & 63;
  int ln15 = lane & 15, q = lane >> 4;

  float avs[12], avd[12];
#pragma unroll
  for (int f = 0; f < 12; ++f) {
    int idx = (f >> 1) * 32 + (f & 1) * 16 + ln15;
    avs[f] = a1s[idx];
    avd[f] = a1d[idx];
  }

  floatx4 acc[12];
#pragma unroll
  for (int f = 0; f < 12; ++f) acc[f] = (floatx4){0.f, 0.f, 0.f, 0.f};

  int arowi = m0 + ln15;
  if (arowi >= N) arowi = N - 1;          // clamp: loads stay in-bounds, stores are guarded
  const float* arow = x + (size_t)arowi * F_IN + q * 8;

#pragma unroll
  for (int kc = 0; kc < F_IN; kc += 32) {
    __syncthreads();
    // stage W1[kc..kc+32) transposed into LDS: 192 x 32 halfs
    for (int j = threadIdx.x; j < 192 * 32; j += 256) {
      int kk = j / 192, n = j - kk * 192;          // consecutive j -> consecutive n (coalesced)
      wlds[n][kk] = (_Float16)W1[(size_t)(kc + kk) * D1 + n];
    }
    __syncthreads();

    float4 u0 = *(const float4*)(arow + kc);
    float4 u1 = *(const float4*)(arow + kc + 4);
    half8 a;
    a[0] = (_Float16)u0.x; a[1] = (_Float16)u0.y; a[2] = (_Float16)u0.z; a[3] = (_Float16)u0.w;
    a[4] = (_Float16)u1.x; a[5] = (_Float16)u1.y; a[6] = (_Float16)u1.z; a[7] = (_Float16)u1.w;
#pragma unroll
    for (int f = 0; f < 12; ++f) {
      half8 b = *(const half8*)(&wlds[16 * f + ln15][q * 8]);
      acc[f] = __builtin_amdgcn_mfma_f32_16x16x32_f16(a, b, acc[f], 0, 0, 0);
    }
  }

#pragma unroll
  for (int f = 0; f < 12; ++f) {
#pragma unroll
    for (int r = 0; r < 4; ++r) {
      int n = m0 + q * 4 + r;
      if (n < N) h1h[(size_t)n * D1 + 16 * f + ln15] = __float2half(acc[f][r]);
    }
  }

#pragma unroll
  for (int r = 0; r < 4; ++r) {
    float ps[6] = {0.f, 0.f, 0.f, 0.f, 0.f, 0.f};
    float pd[6] = {0.f, 0.f, 0.f, 0.f, 0.f, 0.f};
#pragma unroll
    for (int f = 0; f < 12; ++f) {
      ps[f >> 1] = fmaf(acc[f][r], avs[f], ps[f >> 1]);
      pd[f >> 1] = fmaf(acc[f][r], avd[f], pd[f >> 1]);
    }
#pragma unroll
    for (int h = 0; h < 6; ++h) {
#pragma unroll
      for (int m = 8; m; m >>= 1) {
        ps[h] += __shfl_xor(ps[h], m);
        pd[h] += __shfl_xor(pd[h], m);
      }
    }
    float os = 0.f, od = 0.f;
#pragma unroll
    for (int h = 0; h < 6; ++h)
      if (ln15 == h) { os = ps[h]; od = pd[h]; }
    int n = m0 + q * 4 + r;
    if (ln15 < 6 && n < N) {
      als[(size_t)n * 6 + ln15] = os;
      ald[(size_t)n * 6 + ln15] = od;
    }
  }
}

// ---------------- single-block full exclusive scan (N <= 52*1024) ----------------
__global__ __launch_bounds__(1024) void k_scan(const int* __restrict__ cnt,
                                               int* __restrict__ offs, int N) {
  constexpr int MAXR = 52;
  int t = threadIdx.x, lane = t & 63, wid = t >> 6;
  int R = (N + 1023) >> 10;
  __shared__ int wsum[16];
  int v[MAXR];
#pragma unroll
  for (int r = 0; r < MAXR; ++r) {
    int i = (r << 10) + t;
    v[r] = (r < R && i < N) ? cnt[i] : 0;
  }
  int carry = 0;
#pragma unroll
  for (int r = 0; r < MAXR; ++r) {
    if (r >= R) break;
    int incl = v[r];
#pragma unroll
    for (int d = 1; d < 64; d <<= 1) {
      int u = __shfl_up(incl, d);
      if (lane >= d) incl += u;
    }
    if (lane == 63) wsum[wid] = incl;
    __syncthreads();
    if (t < 16) {
      int s = wsum[t];
#pragma unroll
      for (int d = 1; d < 16; d <<= 1) {
        int u = __shfl_up(s, d);
        if (t >= d) s += u;
      }
      wsum[t] = s;   // inclusive over waves
    }
    __syncthreads();
    int wexcl = wid ? wsum[wid - 1] : 0;
    int total = wsum[15];
    int i = (r << 10) + t;
    if (i < N) offs[i] = carry + wexcl + incl - v[r];
    carry += total;
    __syncthreads();
  }
  if (t == 0) offs[N] = carry;
}

// ---------------- place: atomic-free scatter ----------------
__global__ __launch_bounds__(256) void k_place(const int* __restrict__ src,
                                               const int* __restrict__ dst,
                                               const int* __restrict__ offs,
                                               const int* __restrict__ pose,
                                               int* __restrict__ ssort, int E) {
  int e = blockIdx.x * 256 + threadIdx.x;
  if (e < E) {
    ssort[offs[dst[e]] + pose[e]] = src[e];
  }
}

// ---------------- layer-1 aggregation + fused layer-2 node transform ----------------
__global__ __launch_bounds__(256) void k_agg1(
    const __half* __restrict__ h1h, const float* __restrict__ als, const float* __restrict__ ald,
    const int* __restrict__ offs, const int* __restrict__ srcs,
    const float* __restrict__ b1, const float* __restrict__ W2,
    const float* __restrict__ a2s, const float* __restrict__ a2d,
    float4* __restrict__ pk, int N) {   // pk[d] = {h2x, h2y, al2s, al2d}
  __shared__ float wbuf[4][64][9];
  int wid = threadIdx.x >> 6, lane = threadIdx.x & 63;
  int d = blockIdx.x * 4 + wid;
  if (d >= N) return;
  int off = offs[d], cnt = offs[d + 1] - off;
  int tot = cnt + 1;

  float aldh[6];
  {
    const float* ap = ald + (size_t)d * 6;
    float2 q0 = *(const float2*)ap, q1 = *(const float2*)(ap + 2), q2 = *(const float2*)(ap + 4);
    aldh[0] = q0.x; aldh[1] = q0.y; aldh[2] = q1.x;
    aldh[3] = q1.y; aldh[4] = q2.x; aldh[5] = q2.y;
  }

  float dh[6] = {0.f, 0.f, 0.f, 0.f, 0.f, 0.f};
  int nchunk = (tot + 63) >> 6;

  float a0 = 0.f, a1 = 0.f, a2 = 0.f;
  const int hw = lane >> 4;
  const int hh = 4 + (lane >> 5);

  auto body = [&](int j) {
    float w_a = wbuf[wid][j][hw];
    float w_b = wbuf[wid][j][hh];
    int soff = __float_as_int(wbuf[wid][j][6]);   // byte offset = s * 384
    const __half* hp = (const __half*)((const char*)h1h + soff);
    float2 v = __half22float2(*(const __half2*)(hp + 2 * lane));
    float vh = __half2float(hp[128 + lane]);
    a0 = fmaf(w_a, v.x, a0);
    a1 = fmaf(w_a, v.y, a1);
    a2 = fmaf(w_b, vh, a2);
  };
  auto jloop = [&](int jmax) {
    int j = 0;
    for (; j + 3 < jmax; j += 4) { body(j); body(j + 1); body(j + 2); body(j + 3); }
    for (; j < jmax; ++j) body(j);
  };

  if (nchunk == 1) {
    float wreg[6];
    int sreg = 0;
    if (lane < tot) {
      int s = (lane == cnt) ? d : srcs[off + lane];
      sreg = s;
      const float* ap = als + (size_t)s * 6;
      float2 p0 = *(const float2*)ap, p1 = *(const float2*)(ap + 2), p2 = *(const float2*)(ap + 4);
      float ev[6] = {p0.x, p0.y, p1.x, p1.y, p2.x, p2.y};
#pragma unroll
      for (int h = 0; h < 6; ++h) {
        float e = ev[h] + aldh[h];
        e = LRELU(e);
        wreg[h] = __expf(e);
        dh[h] = wreg[h];
      }
    }
#pragma unroll
    for (int h = 0; h < 6; ++h) {
#pragma unroll
      for (int m = 32; m; m >>= 1) dh[h] += __shfl_xor(dh[h], m);
      dh[h] = 1.0f / dh[h];
    }
    if (lane < tot) {
#pragma unroll
      for (int h = 0; h < 6; ++h) wbuf[wid][lane][h] = wreg[h] * dh[h];
      wbuf[wid][lane][6] = __int_as_float(sreg * (D1 * 2));
    }
    wave_lds_fence();
    jloop(tot);
  } else {
    for (int c = 0; c < nchunk; ++c) {
      int i = c * 64 + lane;
      if (i < tot) {
        int s = (i == cnt) ? d : srcs[off + i];
        const float* ap = als + (size_t)s * 6;
        float2 p0 = *(const float2*)ap, p1 = *(const float2*)(ap + 2), p2 = *(const float2*)(ap + 4);
        float ev[6] = {p0.x, p0.y, p1.x, p1.y, p2.x, p2.y};
#pragma unroll
        for (int h = 0; h < 6; ++h) {
          float e = ev[h] + aldh[h];
          e = LRELU(e);
          dh[h] += __expf(e);
        }
      }
    }
#pragma unroll
    for (int h = 0; h < 6; ++h) {
#pragma unroll
      for (int m = 32; m; m >>= 1) dh[h] += __shfl_xor(dh[h], m);
      dh[h] = 1.0f / dh[h];
    }
    for (int c = 0; c < nchunk; ++c) {
      int i = c * 64 + lane;
      if (i < tot) {
        int s = (i == cnt) ? d : srcs[off + i];
        const float* ap = als + (size_t)s * 6;
        float2 p0 = *(const float2*)ap, p1 = *(const float2*)(ap + 2), p2 = *(const float2*)(ap + 4);
        float ev[6] = {p0.x, p0.y, p1.x, p1.y, p2.x, p2.y};
#pragma unroll
        for (int h = 0; h < 6; ++h) {
          float e = ev[h] + aldh[h];
          e = LRELU(e);
          wbuf[wid][lane][h] = __expf(e) * dh[h];
        }
        wbuf[wid][lane][6] = __int_as_float(s * (D1 * 2));
      }
      wave_lds_fence();
      int jmax = tot - c * 64;
      if (jmax > 64) jmax = 64;
      jloop(jmax);
      wave_lds_fence();
    }
  }

  float2 bv = *(const float2*)(b1 + 2 * lane);
  float v0 = fmaxf(a0 + bv.x, 0.f);
  float v1 = fmaxf(a1 + bv.y, 0.f);
  float v2 = fmaxf(a2 + b1[128 + lane], 0.f);
  float4 ww = *(const float4*)(W2 + 4 * lane);
  float2 wh = *(const float2*)(W2 + (128 + lane) * 2);
  float s0 = v0 * ww.x + v1 * ww.z + v2 * wh.x;
  float s1 = v0 * ww.y + v1 * ww.w + v2 * wh.y;
#pragma unroll
  for (int m = 32; m; m >>= 1) {
    s0 += __shfl_xor(s0, m);
    s1 += __shfl_xor(s1, m);
  }
  if (lane == 0) {
    pk[d] = make_float4(s0, s1,
                        s0 * a2s[0] + s1 * a2s[1],
                        s0 * a2d[0] + s1 * a2d[1]);
  }
}

// ---------------- layer-2 aggregation + bias + log_softmax ----------------
__global__ __launch_bounds__(256) void k_agg2(
    const float4* __restrict__ pk, const int* __restrict__ offs,
    const int* __restrict__ srcs, const float* __restrict__ b2,
    float* __restrict__ out, int N) {
  int tid = blockIdx.x * 256 + threadIdx.x;
  int g = tid >> 3, r = tid & 7;
  if (g >= N) return;
  int off = offs[g], cnt = offs[g + 1] - off;
  int tot = cnt + 1;
  float ad = pk[g].w;
  float den = 0.f, o0 = 0.f, o1 = 0.f;
  for (int i = r; i < tot; i += 8) {
    int s = (i == cnt) ? g : srcs[off + i];
    float4 p = pk[s];
    float e = p.z + ad;
    e = LRELU(e);
    float a = __expf(e);
    den += a;
    o0 = fmaf(a, p.x, o0);
    o1 = fmaf(a, p.y, o1);
  }
#pragma unroll
  for (int m = 4; m; m >>= 1) {
    den += __shfl_xor(den, m);
    o0 += __shfl_xor(o0, m);
    o1 += __shfl_xor(o1, m);
  }
  if (r == 0) {
    float inv = 1.0f / den;
    o0 = o0 * inv + b2[0];
    o1 = o1 * inv + b2[1];
    float mm = fmaxf(o0, o1);
    float l = mm + logf(__expf(o0 - mm) + __expf(o1 - mm));
    *(float2*)(out + (size_t)g * 2) = make_float2(o0 - l, o1 - l);
  }
}

extern "C" void kernel_launch(void* const* d_in, const int* in_sizes, int n_in,
                              void* d_out, int out_size, void* d_ws, size_t ws_size,
                              hipStream_t stream) {
  const float* x   = (const float*)d_in[0];
  const int*   ei  = (const int*)d_in[1];
  const float* W1  = (const float*)d_in[2];
  const float* a1s = (const float*)d_in[3];
  const float* a1d = (const float*)d_in[4];
  const float* b1  = (const float*)d_in[5];
  const float* W2  = (const float*)d_in[6];
  const float* a2s = (const float*)d_in[7];
  const float* a2d = (const float*)d_in[8];
  const float* b2  = (const float*)d_in[9];
  float* out = (float*)d_out;

  const int N = in_sizes[0] / F_IN;   // 50000
  const int E = in_sizes[1] / 2;      // 800000
  const int* srcp = ei;
  const int* dstp = ei + E;

  char* w = (char*)d_ws;
  auto alloc = [&](size_t bytes) {
    char* p = w;
    w += (bytes + 255) & ~(size_t)255;
    return p;
  };
  __half* h1h   = (__half*)alloc((size_t)N * D1 * 2 + 256);
  float* als    = (float*)alloc((size_t)N * NH1 * 4);
  float* ald    = (float*)alloc((size_t)N * NH1 * 4);
  float4* pk    = (float4*)alloc((size_t)N * 16);
  int*   cnt    = (int*)alloc((size_t)N * 4);
  int*   offs   = (int*)alloc((size_t)(N + 1) * 4);
  int*   pose   = (int*)alloc((size_t)E * 4);
  int*   ssort  = (int*)alloc((size_t)E * 4);

  const int HB = (E + 255) / 256;                 // 3125 hist blocks
  const int GB = ((N + 15) / 16 + 3) / 4;         // 782 gemm blocks

  hipMemsetAsync(cnt, 0, (size_t)N * 4, stream);

  k_fused<<<HB + GB, 256, 0, stream>>>(dstp, cnt, pose, x, W1, a1s, a1d,
                                       h1h, als, ald, N, E, HB);
  k_scan<<<1, 1024, 0, stream>>>(cnt, offs, N);
  k_place<<<(E + 255) / 256, 256, 0, stream>>>(srcp, dstp, offs, pose, ssort, E);
  k_agg1<<<(N + 3) / 4, 256, 0, stream>>>(h1h, als, ald, offs, ssort, b1, W2,
                                          a2s, a2d, pk, N);
  k_agg2<<<(N * 8 + 255) / 256, 256, 0, stream>>>(pk, offs, ssort, b2, out, N);
}